// Round 5
// baseline (294.674 us; speedup 1.0000x reference)
//
#include <hip/hip_runtime.h>

#define N_NODES 10000
#define N_EDGES 160000
#define E_TOT   170000   // + self loops
#define H1      8
#define C1      120
#define F1      960      // H1*C1

__device__ __forceinline__ float lrelu(float v) { return fmaxf(v, 0.2f * v); }

// ---------------- weight prep ----------------
// W8[c][8] = {Wl[0..3][c], Wr[0..3][c]}; B2[c] = {b1l[c]+b1r[c], att1[c]}
// WltG[c]  = float4 of Wl column c;      PB[c] = {b1l[c], bias1[c]}
// P[h*9..] = {pl[4]=Σ att wl, pr[4]=Σ att wr, pc=Σ att (b1l+b1r)}  (P pre-zeroed by memset)
__global__ void pack_weights(const float* __restrict__ W1l, const float* __restrict__ W1r,
                             const float* __restrict__ b1l, const float* __restrict__ b1r,
                             const float* __restrict__ att1, const float* __restrict__ bias1,
                             float* __restrict__ W8, float* __restrict__ B2,
                             float4* __restrict__ WltG, float2* __restrict__ PB,
                             float* __restrict__ P) {
    int c = threadIdx.x;   // one block, 960 threads
    float wl0 = W1l[c], wl1 = W1l[F1+c], wl2 = W1l[2*F1+c], wl3 = W1l[3*F1+c];
    float wr0 = W1r[c], wr1 = W1r[F1+c], wr2 = W1r[2*F1+c], wr3 = W1r[3*F1+c];
    float bc = b1l[c] + b1r[c];
    float a  = att1[c];
    float* w8 = W8 + c*8;
    w8[0]=wl0; w8[1]=wl1; w8[2]=wl2; w8[3]=wl3;
    w8[4]=wr0; w8[5]=wr1; w8[6]=wr2; w8[7]=wr3;
    B2[c*2] = bc; B2[c*2+1] = a;
    WltG[c] = make_float4(wl0, wl1, wl2, wl3);
    PB[c] = make_float2(b1l[c], bias1[c]);
    float* p = P + (c / C1) * 9;
    atomicAdd(&p[0], a*wl0); atomicAdd(&p[1], a*wl1);
    atomicAdd(&p[2], a*wl2); atomicAdd(&p[3], a*wl3);
    atomicAdd(&p[4], a*wr0); atomicAdd(&p[5], a*wr1);
    atomicAdd(&p[6], a*wr2); atomicAdd(&p[7], a*wr3);
    atomicAdd(&p[8], a*bc);
}

// per-node linear logit parts: Ls[n,h] = x_n·pl_h ; Lr[n,h] = x_n·pr_h + pc_h
__global__ void node_linear(const float* __restrict__ x, const float* __restrict__ P,
                            float* __restrict__ Ls, float* __restrict__ Lr) {
    int n = blockIdx.x * 256 + threadIdx.x;
    if (n >= N_NODES) return;
    float4 xv = ((const float4*)x)[n];
#pragma unroll
    for (int h = 0; h < H1; ++h) {
        const float* p = P + h*9;
        Ls[n*8+h] = xv.x*p[0] + xv.y*p[1] + xv.z*p[2] + xv.w*p[3];
        Lr[n*8+h] = xv.x*p[4] + xv.y*p[5] + xv.z*p[6] + xv.w*p[7] + p[8];
    }
}

// ---------------- CSR build (dst -> incoming edges) ----------------

__global__ void deg_count(const int* __restrict__ ei, int* __restrict__ deg) {
    int e = blockIdx.x * blockDim.x + threadIdx.x;
    if (e >= E_TOT) return;
    int d = (e < N_EDGES) ? ei[N_EDGES + e] : (e - N_EDGES);
    atomicAdd(&deg[d], 1);
}

#define SCAN_T 1024
#define SCAN_I 10
__global__ void scan_rowptr(const int* __restrict__ deg,
                            int* __restrict__ rowptr, int* __restrict__ cur) {
    __shared__ int part[SCAN_T];
    int t = threadIdx.x;
    int base = t * SCAN_I;
    int vals[SCAN_I]; int sum = 0;
#pragma unroll
    for (int i = 0; i < SCAN_I; ++i) {
        int idx = base + i;
        vals[i] = (idx < N_NODES) ? deg[idx] : 0;
        sum += vals[i];
    }
    part[t] = sum;
    __syncthreads();
    for (int off = 1; off < SCAN_T; off <<= 1) {
        int v = (t >= off) ? part[t - off] : 0;
        __syncthreads();
        part[t] += v;
        __syncthreads();
    }
    int run = (t > 0) ? part[t - 1] : 0;
#pragma unroll
    for (int i = 0; i < SCAN_I; ++i) {
        int idx = base + i;
        if (idx < N_NODES) { rowptr[idx] = run; cur[idx] = run; }
        run += vals[i];
    }
    if (t == SCAN_T - 1) rowptr[N_NODES] = run;
}

__global__ void fill_csr(const int* __restrict__ ei, int* __restrict__ cur,
                         int* __restrict__ epos, int* __restrict__ slist) {
    int e = blockIdx.x * blockDim.x + threadIdx.x;
    if (e >= E_TOT) return;
    int s, d;
    if (e < N_EDGES) { s = ei[e]; d = ei[N_EDGES + e]; } else { s = e - N_EDGES; d = s; }
    int pos = atomicAdd(&cur[d], 1);
    epos[e] = pos;
    slist[pos] = s;
}

// ---------------- layer-1 logits -> exp(e), CSR-ordered. thread per (edge, head-quad) ----------------
// e_h = 0.6*(Ls[s,h]+Lr[d,h]) + 0.4 * sum_c att_c * |t_c|,  t_c = bcomb_c + xs·wl_c + xd·wr_c

__global__ void logits1_k(const int* __restrict__ ei, const float* __restrict__ x,
                          const float* __restrict__ W8, const float* __restrict__ B2,
                          const float* __restrict__ Ls, const float* __restrict__ Lr,
                          const int* __restrict__ epos, float* __restrict__ e1) {
    int e = blockIdx.x * 256 + threadIdx.x;
    if (e >= E_TOT) return;
    int s, d;
    if (e < N_EDGES) { s = ei[e]; d = ei[N_EDGES + e]; } else { s = e - N_EDGES; d = s; }
    float4 xs = ((const float4*)x)[s];
    float4 xd = ((const float4*)x)[d];
    int hg = blockIdx.y;   // head quad: 0 -> h0..3, 1 -> h4..7 (wave-uniform)
    float4 lsv = ((const float4*)Ls)[s*2 + hg];
    float4 lrv = ((const float4*)Lr)[d*2 + hg];
    float eo[4];
#pragma unroll
    for (int hh = 0; hh < 4; ++hh) {
        int cb = (hg*4 + hh) * C1;     // uniform
        float aa = 0.f;
#pragma unroll 4
        for (int u = 0; u < C1; ++u) {
            const float* w = W8 + (size_t)(cb + u) * 8;
            float bc = B2[(cb+u)*2], at = B2[(cb+u)*2 + 1];
            float t = bc + xs.x*w[0] + xs.y*w[1] + xs.z*w[2] + xs.w*w[3]
                         + xd.x*w[4] + xd.y*w[5] + xd.z*w[6] + xd.w*w[7];
            aa = fmaf(at, fabsf(t), aa);
        }
        float lin = (hh==0 ? lsv.x : hh==1 ? lsv.y : hh==2 ? lsv.z : lsv.w)
                  + (hh==0 ? lrv.x : hh==1 ? lrv.y : hh==2 ? lrv.z : lrv.w);
        eo[hh] = __expf(0.6f*lin + 0.4f*aa);
    }
    *(float4*)(e1 + (size_t)epos[e]*8 + hg*4) = make_float4(eo[0], eo[1], eo[2], eo[3]);
}

// ---------------- layer-1: single-pass agg (x-space) + expand + relu + layer-2 transform ----------------
// 16 lanes per node, 4 nodes per wave, 16 nodes per block; grid = N_NODES/16

#define AGG(hi, wv) { float W_ = (wv); ssum[hi] += W_; ag[hi].x += W_*xv.x; ag[hi].y += W_*xv.y; ag[hi].z += W_*xv.z; ag[hi].w += W_*xv.w; }

__global__ void fused_agg1(const int* __restrict__ rowptr, const int* __restrict__ slist,
                           const float* __restrict__ e1, const float* __restrict__ x,
                           const float4* __restrict__ WltG, const float2* __restrict__ PB,
                           const float* __restrict__ W2l, const float* __restrict__ W2r,
                           const float* __restrict__ b2l, const float* __restrict__ b2r,
                           float* __restrict__ xl2, float* __restrict__ xr2) {
    int tid = threadIdx.x;
    int node = blockIdx.x * 16 + (tid >> 4);
    int l = tid & 15;
    int beg = rowptr[node], end = rowptr[node + 1];

    float ssum[H1]; float4 ag[H1];
#pragma unroll
    for (int h = 0; h < H1; ++h) { ssum[h] = 0.f; ag[h] = make_float4(0.f,0.f,0.f,0.f); }

    for (int i = beg + l; i < end; i += 16) {
        const float4* p = (const float4*)(e1 + (size_t)i * 8);
        float4 wa = p[0], wb = p[1];
        float4 xv = ((const float4*)x)[slist[i]];
        AGG(0, wa.x) AGG(1, wa.y) AGG(2, wa.z) AGG(3, wa.w)
        AGG(4, wb.x) AGG(5, wb.y) AGG(6, wb.z) AGG(7, wb.w)
    }
#pragma unroll
    for (int off = 8; off; off >>= 1) {
#pragma unroll
        for (int h = 0; h < H1; ++h) {
            ssum[h] += __shfl_xor(ssum[h], off, 64);
            ag[h].x += __shfl_xor(ag[h].x, off, 64);
            ag[h].y += __shfl_xor(ag[h].y, off, 64);
            ag[h].z += __shfl_xor(ag[h].z, off, 64);
            ag[h].w += __shfl_xor(ag[h].w, off, 64);
        }
    }
    float sa[H1];
#pragma unroll
    for (int h = 0; h < H1; ++h) {
        float inv = 1.f / (ssum[h] + 1e-16f);
        ag[h].x *= inv; ag[h].y *= inv; ag[h].z *= inv; ag[h].w *= inv;
        sa[h] = ssum[h] * inv;
    }

    // expand 960 channels over 16 lanes, fused with layer-2 dot
    float al0=0, al1=0, al2=0, al3=0, ar0=0, ar1=0, ar2=0, ar3=0;
#pragma unroll
    for (int h = 0; h < H1; ++h) {
#pragma unroll
        for (int jj = 0; jj < 8; ++jj) {
            int u = l + 16*jj;
            if (u < C1) {
                int c = h*C1 + u;
                float4 wv = WltG[c];
                float2 pb = PB[c];
                float hb = fmaxf(ag[h].x*wv.x + ag[h].y*wv.y + ag[h].z*wv.z + ag[h].w*wv.w
                                 + sa[h]*pb.x + pb.y, 0.f);
                float4 wl = ((const float4*)W2l)[c];
                float4 wr = ((const float4*)W2r)[c];
                al0 += hb*wl.x; al1 += hb*wl.y; al2 += hb*wl.z; al3 += hb*wl.w;
                ar0 += hb*wr.x; ar1 += hb*wr.y; ar2 += hb*wr.z; ar3 += hb*wr.w;
            }
        }
    }
#pragma unroll
    for (int off = 8; off; off >>= 1) {
        al0 += __shfl_xor(al0, off, 64); al1 += __shfl_xor(al1, off, 64);
        al2 += __shfl_xor(al2, off, 64); al3 += __shfl_xor(al3, off, 64);
        ar0 += __shfl_xor(ar0, off, 64); ar1 += __shfl_xor(ar1, off, 64);
        ar2 += __shfl_xor(ar2, off, 64); ar3 += __shfl_xor(ar3, off, 64);
    }
    if (l == 0) {
        ((float4*)xl2)[node] = make_float4(al0 + b2l[0], al1 + b2l[1], al2 + b2l[2], al3 + b2l[3]);
        ((float4*)xr2)[node] = make_float4(ar0 + b2r[0], ar1 + b2r[1], ar2 + b2r[2], ar3 + b2r[3]);
    }
}

// ---------------- layer-2: single-pass logits+softmax+agg+bias; 16 lanes per node ----------------

__global__ void attn2(const int* __restrict__ rowptr, const int* __restrict__ slist,
                      const float* __restrict__ xl2, const float* __restrict__ xr2,
                      const float* __restrict__ att2, const float* __restrict__ bias2,
                      float* __restrict__ out) {
    int tid = threadIdx.x;
    int node = blockIdx.x * 16 + (tid >> 4);
    int l = tid & 15;
    int beg = rowptr[node], end = rowptr[node + 1];
    float4 xr = ((const float4*)xr2)[node];
    float a0 = att2[0], a1 = att2[1], a2 = att2[2], a3 = att2[3];

    float ssum = 0.f;
    float4 acc = make_float4(0.f, 0.f, 0.f, 0.f);
    for (int i = beg + l; i < end; i += 16) {
        float4 v = ((const float4*)xl2)[slist[i]];
        float lg = a0*lrelu(v.x + xr.x) + a1*lrelu(v.y + xr.y)
                 + a2*lrelu(v.z + xr.z) + a3*lrelu(v.w + xr.w);
        float w = __expf(lg);
        ssum += w;
        acc.x += w*v.x; acc.y += w*v.y; acc.z += w*v.z; acc.w += w*v.w;
    }
#pragma unroll
    for (int off = 8; off; off >>= 1) {
        ssum  += __shfl_xor(ssum,  off, 64);
        acc.x += __shfl_xor(acc.x, off, 64);
        acc.y += __shfl_xor(acc.y, off, 64);
        acc.z += __shfl_xor(acc.z, off, 64);
        acc.w += __shfl_xor(acc.w, off, 64);
    }
    if (l == 0) {
        float inv = 1.f / (ssum + 1e-16f);
        ((float4*)out)[node] = make_float4(acc.x*inv + bias2[0], acc.y*inv + bias2[1],
                                           acc.z*inv + bias2[2], acc.w*inv + bias2[3]);
    }
}

extern "C" void kernel_launch(void* const* d_in, const int* in_sizes, int n_in,
                              void* d_out, int out_size, void* d_ws, size_t ws_size,
                              hipStream_t stream) {
    const float* x     = (const float*)d_in[0];
    const int*   ei    = (const int*)  d_in[1];
    const float* W1l   = (const float*)d_in[2];
    const float* W1r   = (const float*)d_in[3];
    const float* b1l   = (const float*)d_in[4];
    const float* b1r   = (const float*)d_in[5];
    const float* att1  = (const float*)d_in[6];
    const float* bias1 = (const float*)d_in[7];
    const float* W2l   = (const float*)d_in[8];
    const float* W2r   = (const float*)d_in[9];
    const float* b2l   = (const float*)d_in[10];
    const float* b2r   = (const float*)d_in[11];
    const float* att2  = (const float*)d_in[12];
    const float* bias2 = (const float*)d_in[13];
    float* out = (float*)d_out;

    // workspace carve-up (floats; every segment size is a multiple of 4)
    float* e1   = (float*)d_ws;                   // E_TOT*8 = 1,360,000
    float* Ls   = e1 + (size_t)E_TOT * 8;         // 80,000
    float* Lr   = Ls + 80000;                     // 80,000
    float* xl2  = Lr + 80000;                     // 40,000
    float* xr2  = xl2 + 40000;                    // 40,000
    float* W8   = xr2 + 40000;                    // 7,680
    float* B2   = W8 + 7680;                      // 1,920
    float* Wltf = B2 + 1920;                      // 3,840 (float4[960])
    float* PBf  = Wltf + 3840;                    // 1,920 (float2[960])
    int* deg    = (int*)(PBf + 1920);             // 10,000
    float* P    = (float*)(deg + 10000);          // 80 (72 used)
    int* rowptr = (int*)(P + 80);                 // 10,004 (10,001 used)
    int* cur    = rowptr + 10004;                 // 10,000
    int* epos   = cur + 10000;                    // 170,000
    int* slist  = epos + 170000;                  // 170,000

    const int B = 256;

    // one memset covers deg (ints) + P (floats), contiguous
    hipMemsetAsync(deg, 0, (10000 + 80) * 4, stream);

    pack_weights<<<1, 960, 0, stream>>>(W1l, W1r, b1l, b1r, att1, bias1,
                                        W8, B2, (float4*)Wltf, (float2*)PBf, P);
    node_linear<<<40, 256, 0, stream>>>(x, P, Ls, Lr);

    deg_count<<<(E_TOT + B - 1) / B, B, 0, stream>>>(ei, deg);
    scan_rowptr<<<1, SCAN_T, 0, stream>>>(deg, rowptr, cur);
    fill_csr<<<(E_TOT + B - 1) / B, B, 0, stream>>>(ei, cur, epos, slist);

    logits1_k<<<dim3((E_TOT + B - 1) / B, 2), B, 0, stream>>>(
        ei, x, W8, B2, Ls, Lr, epos, e1);
    fused_agg1<<<N_NODES / 16, B, 0, stream>>>(
        rowptr, slist, e1, x, (const float4*)Wltf, (const float2*)PBf,
        W2l, W2r, b2l, b2r, xl2, xr2);
    attn2<<<N_NODES / 16, B, 0, stream>>>(rowptr, slist, xl2, xr2, att2, bias2, out);
}

// Round 6
// 197.965 us; speedup vs baseline: 1.4885x; 1.4885x over previous
//
#include <hip/hip_runtime.h>

#define N_NODES 10000
#define N_EDGES 160000
#define E_TOT   170000   // + self loops
#define H1      8
#define C1      120
#define F1      960      // H1*C1

__device__ __forceinline__ float lrelu(float v) { return fmaxf(v, 0.2f * v); }

// ---------------- weight prep (pure repack, no atomics) ----------------
// W8[c][8] = {Wl[0..3][c], Wr[0..3][c]}; B2[c] = {b1l[c]+b1r[c], att1[c]}
// WltG[c]  = float4 of Wl column c;      PB[c] = {b1l[c], bias1[c]}
__global__ void pack_weights(const float* __restrict__ W1l, const float* __restrict__ W1r,
                             const float* __restrict__ b1l, const float* __restrict__ b1r,
                             const float* __restrict__ att1, const float* __restrict__ bias1,
                             float* __restrict__ W8, float* __restrict__ B2,
                             float4* __restrict__ WltG, float2* __restrict__ PB) {
    int c = threadIdx.x;   // one block, 960 threads
    float wl0 = W1l[c], wl1 = W1l[F1+c], wl2 = W1l[2*F1+c], wl3 = W1l[3*F1+c];
    float wr0 = W1r[c], wr1 = W1r[F1+c], wr2 = W1r[2*F1+c], wr3 = W1r[3*F1+c];
    float bc = b1l[c] + b1r[c];
    float a  = att1[c];
    float* w8 = W8 + c*8;
    w8[0]=wl0; w8[1]=wl1; w8[2]=wl2; w8[3]=wl3;
    w8[4]=wr0; w8[5]=wr1; w8[6]=wr2; w8[7]=wr3;
    B2[c*2] = bc; B2[c*2+1] = a;
    WltG[c] = make_float4(wl0, wl1, wl2, wl3);
    PB[c] = make_float2(b1l[c], bias1[c]);
}

// P[h*9+j]: j<4 -> Σ_u att·Wl[j][h,u]; 4..7 -> Σ att·Wr[j-4]; 8 -> Σ att·(b1l+b1r)
// one block, threads 0..71, each a sequential 120-term dot (deterministic, ~µs)
__global__ void compute_P(const float* __restrict__ W1l, const float* __restrict__ W1r,
                          const float* __restrict__ b1l, const float* __restrict__ b1r,
                          const float* __restrict__ att1, float* __restrict__ P) {
    int t = threadIdx.x;
    if (t >= H1 * 9) return;
    int h = t / 9, j = t % 9;
    float acc = 0.f;
    for (int u = 0; u < C1; ++u) {
        int c = h * C1 + u;
        float a = att1[c];
        float w;
        if (j < 4)      w = W1l[j * F1 + c];
        else if (j < 8) w = W1r[(j - 4) * F1 + c];
        else            w = b1l[c] + b1r[c];
        acc = fmaf(a, w, acc);
    }
    P[t] = acc;
}

// per-node linear logit parts: Ls[n,h] = x_n·pl_h ; Lr[n,h] = x_n·pr_h + pc_h
__global__ void node_linear(const float* __restrict__ x, const float* __restrict__ P,
                            float* __restrict__ Ls, float* __restrict__ Lr) {
    int n = blockIdx.x * 256 + threadIdx.x;
    if (n >= N_NODES) return;
    float4 xv = ((const float4*)x)[n];
#pragma unroll
    for (int h = 0; h < H1; ++h) {
        const float* p = P + h*9;
        Ls[n*8+h] = xv.x*p[0] + xv.y*p[1] + xv.z*p[2] + xv.w*p[3];
        Lr[n*8+h] = xv.x*p[4] + xv.y*p[5] + xv.z*p[6] + xv.w*p[7] + p[8];
    }
}

// ---------------- CSR build (dst -> incoming edges) ----------------

__global__ void deg_count(const int* __restrict__ ei, int* __restrict__ deg) {
    int e = blockIdx.x * blockDim.x + threadIdx.x;
    if (e >= E_TOT) return;
    int d = (e < N_EDGES) ? ei[N_EDGES + e] : (e - N_EDGES);
    atomicAdd(&deg[d], 1);
}

#define SCAN_T 1024
#define SCAN_I 10
__global__ void scan_rowptr(const int* __restrict__ deg,
                            int* __restrict__ rowptr, int* __restrict__ cur) {
    __shared__ int part[SCAN_T];
    int t = threadIdx.x;
    int base = t * SCAN_I;
    int vals[SCAN_I]; int sum = 0;
#pragma unroll
    for (int i = 0; i < SCAN_I; ++i) {
        int idx = base + i;
        vals[i] = (idx < N_NODES) ? deg[idx] : 0;
        sum += vals[i];
    }
    part[t] = sum;
    __syncthreads();
    for (int off = 1; off < SCAN_T; off <<= 1) {
        int v = (t >= off) ? part[t - off] : 0;
        __syncthreads();
        part[t] += v;
        __syncthreads();
    }
    int run = (t > 0) ? part[t - 1] : 0;
#pragma unroll
    for (int i = 0; i < SCAN_I; ++i) {
        int idx = base + i;
        if (idx < N_NODES) { rowptr[idx] = run; cur[idx] = run; }
        run += vals[i];
    }
    if (t == SCAN_T - 1) rowptr[N_NODES] = run;
}

__global__ void fill_csr(const int* __restrict__ ei, int* __restrict__ cur,
                         int* __restrict__ epos, int* __restrict__ slist) {
    int e = blockIdx.x * blockDim.x + threadIdx.x;
    if (e >= E_TOT) return;
    int s, d;
    if (e < N_EDGES) { s = ei[e]; d = ei[N_EDGES + e]; } else { s = e - N_EDGES; d = s; }
    int pos = atomicAdd(&cur[d], 1);
    epos[e] = pos;
    slist[pos] = s;
}

// ---------------- layer-1 logits -> exp(e), CSR-ordered. thread per (edge, head-quad) ----------------
// e_h = 0.6*(Ls[s,h]+Lr[d,h]) + 0.4 * sum_c att_c * |t_c|,  t_c = bcomb_c + xs·wl_c + xd·wr_c

__global__ void logits1_k(const int* __restrict__ ei, const float* __restrict__ x,
                          const float* __restrict__ W8, const float* __restrict__ B2,
                          const float* __restrict__ Ls, const float* __restrict__ Lr,
                          const int* __restrict__ epos, float* __restrict__ e1) {
    int e = blockIdx.x * 256 + threadIdx.x;
    if (e >= E_TOT) return;
    int s, d;
    if (e < N_EDGES) { s = ei[e]; d = ei[N_EDGES + e]; } else { s = e - N_EDGES; d = s; }
    float4 xs = ((const float4*)x)[s];
    float4 xd = ((const float4*)x)[d];
    int hg = blockIdx.y;   // head quad: 0 -> h0..3, 1 -> h4..7 (wave-uniform)
    float4 lsv = ((const float4*)Ls)[s*2 + hg];
    float4 lrv = ((const float4*)Lr)[d*2 + hg];
    float eo[4];
#pragma unroll
    for (int hh = 0; hh < 4; ++hh) {
        int cb = (hg*4 + hh) * C1;     // uniform
        float aa = 0.f;
#pragma unroll 4
        for (int u = 0; u < C1; ++u) {
            const float* w = W8 + (size_t)(cb + u) * 8;
            float bc = B2[(cb+u)*2], at = B2[(cb+u)*2 + 1];
            float t = bc + xs.x*w[0] + xs.y*w[1] + xs.z*w[2] + xs.w*w[3]
                         + xd.x*w[4] + xd.y*w[5] + xd.z*w[6] + xd.w*w[7];
            aa = fmaf(at, fabsf(t), aa);
        }
        float lin = (hh==0 ? lsv.x : hh==1 ? lsv.y : hh==2 ? lsv.z : lsv.w)
                  + (hh==0 ? lrv.x : hh==1 ? lrv.y : hh==2 ? lrv.z : lrv.w);
        eo[hh] = __expf(0.6f*lin + 0.4f*aa);
    }
    *(float4*)(e1 + (size_t)epos[e]*8 + hg*4) = make_float4(eo[0], eo[1], eo[2], eo[3]);
}

// ---------------- layer-1: single-pass agg (x-space) + expand + relu + layer-2 transform ----------------
// 16 lanes per node, 4 nodes per wave, 16 nodes per block; grid = N_NODES/16

#define AGG(hi, wv) { float W_ = (wv); ssum[hi] += W_; ag[hi].x += W_*xv.x; ag[hi].y += W_*xv.y; ag[hi].z += W_*xv.z; ag[hi].w += W_*xv.w; }

__global__ void fused_agg1(const int* __restrict__ rowptr, const int* __restrict__ slist,
                           const float* __restrict__ e1, const float* __restrict__ x,
                           const float4* __restrict__ WltG, const float2* __restrict__ PB,
                           const float* __restrict__ W2l, const float* __restrict__ W2r,
                           const float* __restrict__ b2l, const float* __restrict__ b2r,
                           float* __restrict__ xl2, float* __restrict__ xr2) {
    int tid = threadIdx.x;
    int node = blockIdx.x * 16 + (tid >> 4);
    int l = tid & 15;
    int beg = rowptr[node], end = rowptr[node + 1];

    float ssum[H1]; float4 ag[H1];
#pragma unroll
    for (int h = 0; h < H1; ++h) { ssum[h] = 0.f; ag[h] = make_float4(0.f,0.f,0.f,0.f); }

    for (int i = beg + l; i < end; i += 16) {
        const float4* p = (const float4*)(e1 + (size_t)i * 8);
        float4 wa = p[0], wb = p[1];
        float4 xv = ((const float4*)x)[slist[i]];
        AGG(0, wa.x) AGG(1, wa.y) AGG(2, wa.z) AGG(3, wa.w)
        AGG(4, wb.x) AGG(5, wb.y) AGG(6, wb.z) AGG(7, wb.w)
    }
#pragma unroll
    for (int off = 8; off; off >>= 1) {
#pragma unroll
        for (int h = 0; h < H1; ++h) {
            ssum[h] += __shfl_xor(ssum[h], off, 64);
            ag[h].x += __shfl_xor(ag[h].x, off, 64);
            ag[h].y += __shfl_xor(ag[h].y, off, 64);
            ag[h].z += __shfl_xor(ag[h].z, off, 64);
            ag[h].w += __shfl_xor(ag[h].w, off, 64);
        }
    }
    float sa[H1];
#pragma unroll
    for (int h = 0; h < H1; ++h) {
        float inv = 1.f / (ssum[h] + 1e-16f);
        ag[h].x *= inv; ag[h].y *= inv; ag[h].z *= inv; ag[h].w *= inv;
        sa[h] = ssum[h] * inv;
    }

    // expand 960 channels over 16 lanes, fused with layer-2 dot
    float al0=0, al1=0, al2=0, al3=0, ar0=0, ar1=0, ar2=0, ar3=0;
#pragma unroll
    for (int h = 0; h < H1; ++h) {
#pragma unroll
        for (int jj = 0; jj < 8; ++jj) {
            int u = l + 16*jj;
            if (u < C1) {
                int c = h*C1 + u;
                float4 wv = WltG[c];
                float2 pb = PB[c];
                float hb = fmaxf(ag[h].x*wv.x + ag[h].y*wv.y + ag[h].z*wv.z + ag[h].w*wv.w
                                 + sa[h]*pb.x + pb.y, 0.f);
                float4 wl = ((const float4*)W2l)[c];
                float4 wr = ((const float4*)W2r)[c];
                al0 += hb*wl.x; al1 += hb*wl.y; al2 += hb*wl.z; al3 += hb*wl.w;
                ar0 += hb*wr.x; ar1 += hb*wr.y; ar2 += hb*wr.z; ar3 += hb*wr.w;
            }
        }
    }
#pragma unroll
    for (int off = 8; off; off >>= 1) {
        al0 += __shfl_xor(al0, off, 64); al1 += __shfl_xor(al1, off, 64);
        al2 += __shfl_xor(al2, off, 64); al3 += __shfl_xor(al3, off, 64);
        ar0 += __shfl_xor(ar0, off, 64); ar1 += __shfl_xor(ar1, off, 64);
        ar2 += __shfl_xor(ar2, off, 64); ar3 += __shfl_xor(ar3, off, 64);
    }
    if (l == 0) {
        ((float4*)xl2)[node] = make_float4(al0 + b2l[0], al1 + b2l[1], al2 + b2l[2], al3 + b2l[3]);
        ((float4*)xr2)[node] = make_float4(ar0 + b2r[0], ar1 + b2r[1], ar2 + b2r[2], ar3 + b2r[3]);
    }
}

// ---------------- layer-2: single-pass logits+softmax+agg+bias; 16 lanes per node ----------------

__global__ void attn2(const int* __restrict__ rowptr, const int* __restrict__ slist,
                      const float* __restrict__ xl2, const float* __restrict__ xr2,
                      const float* __restrict__ att2, const float* __restrict__ bias2,
                      float* __restrict__ out) {
    int tid = threadIdx.x;
    int node = blockIdx.x * 16 + (tid >> 4);
    int l = tid & 15;
    int beg = rowptr[node], end = rowptr[node + 1];
    float4 xr = ((const float4*)xr2)[node];
    float a0 = att2[0], a1 = att2[1], a2 = att2[2], a3 = att2[3];

    float ssum = 0.f;
    float4 acc = make_float4(0.f, 0.f, 0.f, 0.f);
    for (int i = beg + l; i < end; i += 16) {
        float4 v = ((const float4*)xl2)[slist[i]];
        float lg = a0*lrelu(v.x + xr.x) + a1*lrelu(v.y + xr.y)
                 + a2*lrelu(v.z + xr.z) + a3*lrelu(v.w + xr.w);
        float w = __expf(lg);
        ssum += w;
        acc.x += w*v.x; acc.y += w*v.y; acc.z += w*v.z; acc.w += w*v.w;
    }
#pragma unroll
    for (int off = 8; off; off >>= 1) {
        ssum  += __shfl_xor(ssum,  off, 64);
        acc.x += __shfl_xor(acc.x, off, 64);
        acc.y += __shfl_xor(acc.y, off, 64);
        acc.z += __shfl_xor(acc.z, off, 64);
        acc.w += __shfl_xor(acc.w, off, 64);
    }
    if (l == 0) {
        float inv = 1.f / (ssum + 1e-16f);
        ((float4*)out)[node] = make_float4(acc.x*inv + bias2[0], acc.y*inv + bias2[1],
                                           acc.z*inv + bias2[2], acc.w*inv + bias2[3]);
    }
}

extern "C" void kernel_launch(void* const* d_in, const int* in_sizes, int n_in,
                              void* d_out, int out_size, void* d_ws, size_t ws_size,
                              hipStream_t stream) {
    const float* x     = (const float*)d_in[0];
    const int*   ei    = (const int*)  d_in[1];
    const float* W1l   = (const float*)d_in[2];
    const float* W1r   = (const float*)d_in[3];
    const float* b1l   = (const float*)d_in[4];
    const float* b1r   = (const float*)d_in[5];
    const float* att1  = (const float*)d_in[6];
    const float* bias1 = (const float*)d_in[7];
    const float* W2l   = (const float*)d_in[8];
    const float* W2r   = (const float*)d_in[9];
    const float* b2l   = (const float*)d_in[10];
    const float* b2r   = (const float*)d_in[11];
    const float* att2  = (const float*)d_in[12];
    const float* bias2 = (const float*)d_in[13];
    float* out = (float*)d_out;

    // workspace carve-up (floats; every segment size is a multiple of 4)
    float* e1   = (float*)d_ws;                   // E_TOT*8 = 1,360,000
    float* Ls   = e1 + (size_t)E_TOT * 8;         // 80,000
    float* Lr   = Ls + 80000;                     // 80,000
    float* xl2  = Lr + 80000;                     // 40,000
    float* xr2  = xl2 + 40000;                    // 40,000
    float* W8   = xr2 + 40000;                    // 7,680
    float* B2   = W8 + 7680;                      // 1,920
    float* Wltf = B2 + 1920;                      // 3,840 (float4[960])
    float* PBf  = Wltf + 3840;                    // 1,920 (float2[960])
    int* deg    = (int*)(PBf + 1920);             // 10,000
    float* P    = (float*)(deg + 10000);          // 80 (72 used)
    int* rowptr = (int*)(P + 80);                 // 10,004 (10,001 used)
    int* cur    = rowptr + 10004;                 // 10,000
    int* epos   = cur + 10000;                    // 170,000
    int* slist  = epos + 170000;                  // 170,000

    const int B = 256;

    hipMemsetAsync(deg, 0, 10000 * 4, stream);

    pack_weights<<<1, 960, 0, stream>>>(W1l, W1r, b1l, b1r, att1, bias1,
                                        W8, B2, (float4*)Wltf, (float2*)PBf);
    compute_P<<<1, 128, 0, stream>>>(W1l, W1r, b1l, b1r, att1, P);
    node_linear<<<40, 256, 0, stream>>>(x, P, Ls, Lr);

    deg_count<<<(E_TOT + B - 1) / B, B, 0, stream>>>(ei, deg);
    scan_rowptr<<<1, SCAN_T, 0, stream>>>(deg, rowptr, cur);
    fill_csr<<<(E_TOT + B - 1) / B, B, 0, stream>>>(ei, cur, epos, slist);

    logits1_k<<<dim3((E_TOT + B - 1) / B, 2), B, 0, stream>>>(
        ei, x, W8, B2, Ls, Lr, epos, e1);
    fused_agg1<<<N_NODES / 16, B, 0, stream>>>(
        rowptr, slist, e1, x, (const float4*)Wltf, (const float2*)PBf,
        W2l, W2r, b2l, b2r, xl2, xr2);
    attn2<<<N_NODES / 16, B, 0, stream>>>(rowptr, slist, xl2, xr2, att2, bias2, out);
}

// Round 7
// 140.550 us; speedup vs baseline: 2.0966x; 1.4085x over previous
//
#include <hip/hip_runtime.h>

#define N_NODES 10000
#define N_EDGES 160000
#define E_TOT   170000   // + self loops
#define H1      8
#define C1      120
#define F1      960      // H1*C1

typedef _Float16 h2 __attribute__((ext_vector_type(2)));
union H2U { unsigned u; h2 h; };

#if defined(__has_builtin)
#if __has_builtin(__builtin_amdgcn_fdot2)
#define FDOT2(a,b,c) __builtin_amdgcn_fdot2((a),(b),(c),false)
#endif
#endif
#ifndef FDOT2
#define FDOT2(a,b,c) ((float)(a)[0]*(float)(b)[0] + (float)(a)[1]*(float)(b)[1] + (c))
#endif

__device__ __forceinline__ float lrelu(float v) { return fmaxf(v, 0.2f * v); }
__device__ __forceinline__ unsigned packh2(float a, float b) {
    H2U u; u.h = (h2){(_Float16)a, (_Float16)b}; return u.u;
}

// ---------------- fused prep ----------------
// blocks 0..3   : channel repack (240 ch each):
//   WH[c] = uint4 {wl01, wl23, wr01, wr23} (f16x2); BA[c] = {b1l+b1r, 0.4*att}
//   WltG[c] = float4 Wl column; PB[c] = {b1l, bias1}
// blocks 4..43  : compute P (x0.6) in-block, then 250 nodes each:
//   xh[n] (f16x2 pack), Ls[n,h] = 0.6*x·pl_h, Lr[n,h] = 0.6*(x·pr_h + pc_h)
__global__ __launch_bounds__(256) void prep(
        const float* __restrict__ x,
        const float* __restrict__ W1l, const float* __restrict__ W1r,
        const float* __restrict__ b1l, const float* __restrict__ b1r,
        const float* __restrict__ att1, const float* __restrict__ bias1,
        uint4* __restrict__ WH, float2* __restrict__ BA,
        float4* __restrict__ WltG, float2* __restrict__ PB,
        uint2* __restrict__ xh, float* __restrict__ Ls, float* __restrict__ Lr) {
    int b = blockIdx.x, t = threadIdx.x;
    if (b < 4) {
        int c = b * 240 + t;
        if (t < 240) {
            float wl0 = W1l[c], wl1 = W1l[F1+c], wl2 = W1l[2*F1+c], wl3 = W1l[3*F1+c];
            float wr0 = W1r[c], wr1 = W1r[F1+c], wr2 = W1r[2*F1+c], wr3 = W1r[3*F1+c];
            WH[c] = make_uint4(packh2(wl0, wl1), packh2(wl2, wl3),
                               packh2(wr0, wr1), packh2(wr2, wr3));
            BA[c] = make_float2(b1l[c] + b1r[c], 0.4f * att1[c]);
            WltG[c] = make_float4(wl0, wl1, wl2, wl3);
            PB[c] = make_float2(b1l[c], bias1[c]);
        }
        return;
    }
    __shared__ float Ps[72];
    if (t < 72) {
        int h = t / 9, j = t % 9;
        float acc = 0.f;
        for (int u = 0; u < C1; ++u) {
            int c = h * C1 + u;
            float a = att1[c];
            float w;
            if (j < 4)      w = W1l[j * F1 + c];
            else if (j < 8) w = W1r[(j - 4) * F1 + c];
            else            w = b1l[c] + b1r[c];
            acc = fmaf(a, w, acc);
        }
        Ps[t] = 0.6f * acc;
    }
    __syncthreads();
    int n = (b - 4) * 250 + t;
    if (t < 250) {
        float4 xv = ((const float4*)x)[n];
        xh[n] = make_uint2(packh2(xv.x, xv.y), packh2(xv.z, xv.w));
#pragma unroll
        for (int h = 0; h < H1; ++h) {
            const float* p = Ps + h * 9;
            Ls[n*8+h] = xv.x*p[0] + xv.y*p[1] + xv.z*p[2] + xv.w*p[3];
            Lr[n*8+h] = xv.x*p[4] + xv.y*p[5] + xv.z*p[6] + xv.w*p[7] + p[8];
        }
    }
}

// ---------------- CSR build ----------------

__global__ void deg_count(const int* __restrict__ ei, int* __restrict__ deg) {
    int e = blockIdx.x * blockDim.x + threadIdx.x;
    if (e >= E_TOT) return;
    int d = (e < N_EDGES) ? ei[N_EDGES + e] : (e - N_EDGES);
    atomicAdd(&deg[d], 1);
}

// shfl-based scan: 1024 threads, 10 elems each, 2 barriers
__global__ __launch_bounds__(1024) void scan_rowptr(const int* __restrict__ deg,
                                                    int* __restrict__ rowptr,
                                                    int* __restrict__ cur) {
    __shared__ int wtot[16], wbase[16];
    int t = threadIdx.x, lane = t & 63, w = t >> 6;
    int base = t * 10;
    int vals[10]; int sum = 0;
#pragma unroll
    for (int i = 0; i < 10; ++i) {
        int idx = base + i;
        vals[i] = (idx < N_NODES) ? deg[idx] : 0;
        sum += vals[i];
    }
    int sc = sum;  // inclusive wave scan
#pragma unroll
    for (int off = 1; off < 64; off <<= 1) {
        int v = __shfl_up(sc, off, 64);
        if (lane >= off) sc += v;
    }
    if (lane == 63) wtot[w] = sc;
    __syncthreads();
    if (t < 16) {
        int v = wtot[t];
        int s2 = v;
#pragma unroll
        for (int off = 1; off < 16; off <<= 1) {
            int u = __shfl_up(s2, off, 64);
            if (t >= off) s2 += u;
        }
        wbase[t] = s2 - v;
        if (t == 15) rowptr[N_NODES] = s2;
    }
    __syncthreads();
    int run = wbase[w] + (sc - sum);
#pragma unroll
    for (int i = 0; i < 10; ++i) {
        int idx = base + i;
        if (idx < N_NODES) { rowptr[idx] = run; cur[idx] = run; }
        run += vals[i];
    }
}

__global__ void fill_csr(const int* __restrict__ ei, int* __restrict__ cur,
                         int* __restrict__ epos, int* __restrict__ slist) {
    int e = blockIdx.x * blockDim.x + threadIdx.x;
    if (e >= E_TOT) return;
    int s, d;
    if (e < N_EDGES) { s = ei[e]; d = ei[N_EDGES + e]; } else { s = e - N_EDGES; d = s; }
    int pos = atomicAdd(&cur[d], 1);
    epos[e] = pos;
    slist[pos] = s;
}

// ---------------- layer-1 logits -> exp(e), CSR-ordered ----------------
// thread per (edge, head-quad). e_h = lin + sum_c at'_c * |t_c|, t via 4x fdot2.

__global__ __launch_bounds__(256) void logits1_f16(
        const int* __restrict__ ei, const uint2* __restrict__ xh,
        const uint4* __restrict__ WH, const float2* __restrict__ BA,
        const float* __restrict__ Ls, const float* __restrict__ Lr,
        const int* __restrict__ epos, float* __restrict__ e1) {
    int e = blockIdx.x * 256 + threadIdx.x;
    if (e >= E_TOT) return;
    int s, d;
    if (e < N_EDGES) { s = ei[e]; d = ei[N_EDGES + e]; } else { s = e - N_EDGES; d = s; }
    uint2 xsu = xh[s], xdu = xh[d];
    H2U xs01, xs23, xd01, xd23;
    xs01.u = xsu.x; xs23.u = xsu.y; xd01.u = xdu.x; xd23.u = xdu.y;
    int hg = blockIdx.y;   // head quad (wave-uniform)
    float4 lsv = ((const float4*)Ls)[s*2 + hg];
    float4 lrv = ((const float4*)Lr)[d*2 + hg];
    float eo[4];
#pragma unroll
    for (int hh = 0; hh < 4; ++hh) {
        int cb = (hg*4 + hh) * C1;     // uniform
        float aa = 0.f;
#pragma unroll 8
        for (int u = 0; u < C1; ++u) {
            uint4 wp = WH[cb + u];
            float2 ba = BA[cb + u];
            H2U w0, w1, w2, w3;
            w0.u = wp.x; w1.u = wp.y; w2.u = wp.z; w3.u = wp.w;
            float t = ba.x;
            t = FDOT2(xs01.h, w0.h, t);
            t = FDOT2(xs23.h, w1.h, t);
            t = FDOT2(xd01.h, w2.h, t);
            t = FDOT2(xd23.h, w3.h, t);
            aa = fmaf(ba.y, fabsf(t), aa);
        }
        float lin = (hh==0 ? lsv.x : hh==1 ? lsv.y : hh==2 ? lsv.z : lsv.w)
                  + (hh==0 ? lrv.x : hh==1 ? lrv.y : hh==2 ? lrv.z : lrv.w);
        eo[hh] = __expf(lin + aa);
    }
    *(float4*)(e1 + (size_t)epos[e]*8 + hg*4) = make_float4(eo[0], eo[1], eo[2], eo[3]);
}

// ---------------- layer-1 agg + expand + relu + layer-2 transform ----------------

#define AGG(hi, wv) { float W_ = (wv); ssum[hi] += W_; ag[hi].x += W_*xv.x; ag[hi].y += W_*xv.y; ag[hi].z += W_*xv.z; ag[hi].w += W_*xv.w; }

__global__ __launch_bounds__(256) void fused_agg1(
        const int* __restrict__ rowptr, const int* __restrict__ slist,
        const float* __restrict__ e1, const float* __restrict__ x,
        const float4* __restrict__ WltG, const float2* __restrict__ PB,
        const float* __restrict__ W2l, const float* __restrict__ W2r,
        const float* __restrict__ b2l, const float* __restrict__ b2r,
        float* __restrict__ xl2, float* __restrict__ xr2) {
    int tid = threadIdx.x;
    int node = blockIdx.x * 16 + (tid >> 4);
    int l = tid & 15;
    int beg = rowptr[node], end = rowptr[node + 1];

    float ssum[H1]; float4 ag[H1];
#pragma unroll
    for (int h = 0; h < H1; ++h) { ssum[h] = 0.f; ag[h] = make_float4(0.f,0.f,0.f,0.f); }

    for (int i = beg + l; i < end; i += 16) {
        const float4* p = (const float4*)(e1 + (size_t)i * 8);
        float4 wa = p[0], wb = p[1];
        float4 xv = ((const float4*)x)[slist[i]];
        AGG(0, wa.x) AGG(1, wa.y) AGG(2, wa.z) AGG(3, wa.w)
        AGG(4, wb.x) AGG(5, wb.y) AGG(6, wb.z) AGG(7, wb.w)
    }
#pragma unroll
    for (int off = 8; off; off >>= 1) {
#pragma unroll
        for (int h = 0; h < H1; ++h) {
            ssum[h] += __shfl_xor(ssum[h], off, 64);
            ag[h].x += __shfl_xor(ag[h].x, off, 64);
            ag[h].y += __shfl_xor(ag[h].y, off, 64);
            ag[h].z += __shfl_xor(ag[h].z, off, 64);
            ag[h].w += __shfl_xor(ag[h].w, off, 64);
        }
    }
    float sa[H1];
#pragma unroll
    for (int h = 0; h < H1; ++h) {
        float inv = 1.f / (ssum[h] + 1e-16f);
        ag[h].x *= inv; ag[h].y *= inv; ag[h].z *= inv; ag[h].w *= inv;
        sa[h] = ssum[h] * inv;
    }

    float al0=0, al1=0, al2=0, al3=0, ar0=0, ar1=0, ar2=0, ar3=0;
#pragma unroll
    for (int h = 0; h < H1; ++h) {
#pragma unroll
        for (int jj = 0; jj < 8; ++jj) {
            int u = l + 16*jj;
            if (u < C1) {
                int c = h*C1 + u;
                float4 wv = WltG[c];
                float2 pb = PB[c];
                float hb = fmaxf(ag[h].x*wv.x + ag[h].y*wv.y + ag[h].z*wv.z + ag[h].w*wv.w
                                 + sa[h]*pb.x + pb.y, 0.f);
                float4 wl = ((const float4*)W2l)[c];
                float4 wr = ((const float4*)W2r)[c];
                al0 += hb*wl.x; al1 += hb*wl.y; al2 += hb*wl.z; al3 += hb*wl.w;
                ar0 += hb*wr.x; ar1 += hb*wr.y; ar2 += hb*wr.z; ar3 += hb*wr.w;
            }
        }
    }
#pragma unroll
    for (int off = 8; off; off >>= 1) {
        al0 += __shfl_xor(al0, off, 64); al1 += __shfl_xor(al1, off, 64);
        al2 += __shfl_xor(al2, off, 64); al3 += __shfl_xor(al3, off, 64);
        ar0 += __shfl_xor(ar0, off, 64); ar1 += __shfl_xor(ar1, off, 64);
        ar2 += __shfl_xor(ar2, off, 64); ar3 += __shfl_xor(ar3, off, 64);
    }
    if (l == 0) {
        ((float4*)xl2)[node] = make_float4(al0 + b2l[0], al1 + b2l[1], al2 + b2l[2], al3 + b2l[3]);
        ((float4*)xr2)[node] = make_float4(ar0 + b2r[0], ar1 + b2r[1], ar2 + b2r[2], ar3 + b2r[3]);
    }
}

// ---------------- layer-2 fused attention ----------------

__global__ __launch_bounds__(256) void attn2(
        const int* __restrict__ rowptr, const int* __restrict__ slist,
        const float* __restrict__ xl2, const float* __restrict__ xr2,
        const float* __restrict__ att2, const float* __restrict__ bias2,
        float* __restrict__ out) {
    int tid = threadIdx.x;
    int node = blockIdx.x * 16 + (tid >> 4);
    int l = tid & 15;
    int beg = rowptr[node], end = rowptr[node + 1];
    float4 xr = ((const float4*)xr2)[node];
    float a0 = att2[0], a1 = att2[1], a2 = att2[2], a3 = att2[3];

    float ssum = 0.f;
    float4 acc = make_float4(0.f, 0.f, 0.f, 0.f);
    for (int i = beg + l; i < end; i += 16) {
        float4 v = ((const float4*)xl2)[slist[i]];
        float lg = a0*lrelu(v.x + xr.x) + a1*lrelu(v.y + xr.y)
                 + a2*lrelu(v.z + xr.z) + a3*lrelu(v.w + xr.w);
        float w = __expf(lg);
        ssum += w;
        acc.x += w*v.x; acc.y += w*v.y; acc.z += w*v.z; acc.w += w*v.w;
    }
#pragma unroll
    for (int off = 8; off; off >>= 1) {
        ssum  += __shfl_xor(ssum,  off, 64);
        acc.x += __shfl_xor(acc.x, off, 64);
        acc.y += __shfl_xor(acc.y, off, 64);
        acc.z += __shfl_xor(acc.z, off, 64);
        acc.w += __shfl_xor(acc.w, off, 64);
    }
    if (l == 0) {
        float inv = 1.f / (ssum + 1e-16f);
        ((float4*)out)[node] = make_float4(acc.x*inv + bias2[0], acc.y*inv + bias2[1],
                                           acc.z*inv + bias2[2], acc.w*inv + bias2[3]);
    }
}

extern "C" void kernel_launch(void* const* d_in, const int* in_sizes, int n_in,
                              void* d_out, int out_size, void* d_ws, size_t ws_size,
                              hipStream_t stream) {
    const float* x     = (const float*)d_in[0];
    const int*   ei    = (const int*)  d_in[1];
    const float* W1l   = (const float*)d_in[2];
    const float* W1r   = (const float*)d_in[3];
    const float* b1l   = (const float*)d_in[4];
    const float* b1r   = (const float*)d_in[5];
    const float* att1  = (const float*)d_in[6];
    const float* bias1 = (const float*)d_in[7];
    const float* W2l   = (const float*)d_in[8];
    const float* W2r   = (const float*)d_in[9];
    const float* b2l   = (const float*)d_in[10];
    const float* b2r   = (const float*)d_in[11];
    const float* att2  = (const float*)d_in[12];
    const float* bias2 = (const float*)d_in[13];
    float* out = (float*)d_out;

    // workspace carve-up (all segments multiples of 16 B)
    float* e1   = (float*)d_ws;                   // E_TOT*8 = 1,360,000 f
    float* Ls   = e1 + (size_t)E_TOT * 8;         // 80,000
    float* Lr   = Ls + 80000;                     // 80,000
    float* xl2  = Lr + 80000;                     // 40,000
    float* xr2  = xl2 + 40000;                    // 40,000
    float* WltG = xr2 + 40000;                    // 3,840 (float4[960])
    float* PBf  = WltG + 3840;                    // 1,920 (float2[960])
    unsigned* WHu = (unsigned*)(PBf + 1920);      // 3,840 (uint4[960])
    float* BAf  = (float*)(WHu + 3840);           // 1,920 (float2[960])
    unsigned* xhu = (unsigned*)(BAf + 1920);      // 20,000 (uint2[10000])
    int* deg    = (int*)(xhu + 20000);            // 10,000
    int* rowptr = deg + 10000;                    // 10,004 (10,001 used)
    int* cur    = rowptr + 10004;                 // 10,000
    int* epos   = cur + 10000;                    // 170,000
    int* slist  = epos + 170000;                  // 170,000

    const int B = 256;

    hipMemsetAsync(deg, 0, 10000 * 4, stream);

    prep<<<44, B, 0, stream>>>(x, W1l, W1r, b1l, b1r, att1, bias1,
                               (uint4*)WHu, (float2*)BAf, (float4*)WltG, (float2*)PBf,
                               (uint2*)xhu, Ls, Lr);

    deg_count<<<(E_TOT + B - 1) / B, B, 0, stream>>>(ei, deg);
    scan_rowptr<<<1, 1024, 0, stream>>>(deg, rowptr, cur);
    fill_csr<<<(E_TOT + B - 1) / B, B, 0, stream>>>(ei, cur, epos, slist);

    logits1_f16<<<dim3((E_TOT + B - 1) / B, 2), B, 0, stream>>>(
        ei, (const uint2*)xhu, (const uint4*)WHu, (const float2*)BAf,
        Ls, Lr, epos, e1);
    fused_agg1<<<N_NODES / 16, B, 0, stream>>>(
        rowptr, slist, e1, x, (const float4*)WltG, (const float2*)PBf,
        W2l, W2r, b2l, b2r, xl2, xr2);
    attn2<<<N_NODES / 16, B, 0, stream>>>(rowptr, slist, xl2, xr2, att2, bias2, out);
}

// Round 8
// 134.024 us; speedup vs baseline: 2.1987x; 1.0487x over previous
//
#include <hip/hip_runtime.h>

#define N_NODES 10000
#define N_EDGES 160000
#define E_TOT   170000   // + self loops
#define H1      8
#define C1      120
#define F1      960      // H1*C1

typedef _Float16 h2 __attribute__((ext_vector_type(2)));
union H2U { unsigned u; h2 h; };

#if defined(__has_builtin)
#if __has_builtin(__builtin_amdgcn_fdot2)
#define FDOT2(a,b,c) __builtin_amdgcn_fdot2((a),(b),(c),false)
#endif
#endif
#ifndef FDOT2
#define FDOT2(a,b,c) ((float)(a)[0]*(float)(b)[0] + (float)(a)[1]*(float)(b)[1] + (c))
#endif

__device__ __forceinline__ float lrelu(float v) { return fmaxf(v, 0.2f * v); }
__device__ __forceinline__ unsigned packh2(float a, float b) {
    H2U u; u.h = (h2){(_Float16)a, (_Float16)b}; return u.u;
}
__device__ __forceinline__ h2 toh2(unsigned v) { H2U u; u.u = v; return u.h; }

// ---------------- fused prep (+ deg_count) ----------------
// blocks 0..3: channel repack (c = b*240 + t, t<240):
//   WH[c]  = uint4 {wl01, wl23, wr01, wr23} (f16x2 pairs of Wl/Wr columns)
//   BA[c]  = {b1l+b1r, 0.4*att}
//   WAh[c] = uint2 f16x2 of Wl column; PBh[c] = pk(b1l, bias1)
//   and for i = b*120+t (t<120): W2P pair tables (channels u, u+60)
// blocks 4..43: P (x0.6) in-block; 250 nodes each: xh pack, Ls, Lr
// blocks 44.. : deg_count (deg pre-zeroed by memset)
__global__ __launch_bounds__(256) void prep(
        const float* __restrict__ x, const int* __restrict__ ei,
        const float* __restrict__ W1l, const float* __restrict__ W1r,
        const float* __restrict__ b1l, const float* __restrict__ b1r,
        const float* __restrict__ att1, const float* __restrict__ bias1,
        const float* __restrict__ W2l, const float* __restrict__ W2r,
        uint4* __restrict__ WH, float2* __restrict__ BA,
        uint2* __restrict__ WAh, unsigned* __restrict__ PBh,
        uint4* __restrict__ W2P,
        uint2* __restrict__ xh, float* __restrict__ Ls, float* __restrict__ Lr,
        int* __restrict__ deg) {
    int b = blockIdx.x, t = threadIdx.x;
    if (b >= 44) {
        int e = (b - 44) * 256 + t;
        if (e < E_TOT) {
            int d = (e < N_EDGES) ? ei[N_EDGES + e] : (e - N_EDGES);
            atomicAdd(&deg[d], 1);
        }
        return;
    }
    if (b < 4) {
        if (t < 240) {
            int c = b * 240 + t;
            float wl0 = W1l[c], wl1 = W1l[F1+c], wl2 = W1l[2*F1+c], wl3 = W1l[3*F1+c];
            float wr0 = W1r[c], wr1 = W1r[F1+c], wr2 = W1r[2*F1+c], wr3 = W1r[3*F1+c];
            WH[c] = make_uint4(packh2(wl0, wl1), packh2(wl2, wl3),
                               packh2(wr0, wr1), packh2(wr2, wr3));
            BA[c] = make_float2(b1l[c] + b1r[c], 0.4f * att1[c]);
            WAh[c] = make_uint2(packh2(wl0, wl1), packh2(wl2, wl3));
            PBh[c] = packh2(b1l[c], bias1[c]);
        }
        if (t < 120) {
            int i = b * 120 + t;          // pair index: h = i/60, u = i%60
            int h = i / 60, u = i - h * 60;
            int c0 = h * C1 + u, c1 = c0 + 60;
            const float4 wl0 = ((const float4*)W2l)[c0], wl1 = ((const float4*)W2l)[c1];
            const float4 wr0 = ((const float4*)W2r)[c0], wr1 = ((const float4*)W2r)[c1];
            W2P[i*2]   = make_uint4(packh2(wl0.x, wl1.x), packh2(wl0.y, wl1.y),
                                    packh2(wl0.z, wl1.z), packh2(wl0.w, wl1.w));
            W2P[i*2+1] = make_uint4(packh2(wr0.x, wr1.x), packh2(wr0.y, wr1.y),
                                    packh2(wr0.z, wr1.z), packh2(wr0.w, wr1.w));
        }
        return;
    }
    __shared__ float Ps[72];
    if (t < 72) {
        int h = t / 9, j = t % 9;
        float acc = 0.f;
        for (int u = 0; u < C1; ++u) {
            int c = h * C1 + u;
            float a = att1[c];
            float w;
            if (j < 4)      w = W1l[j * F1 + c];
            else if (j < 8) w = W1r[(j - 4) * F1 + c];
            else            w = b1l[c] + b1r[c];
            acc = fmaf(a, w, acc);
        }
        Ps[t] = 0.6f * acc;
    }
    __syncthreads();
    int n = (b - 4) * 250 + t;
    if (t < 250) {
        float4 xv = ((const float4*)x)[n];
        xh[n] = make_uint2(packh2(xv.x, xv.y), packh2(xv.z, xv.w));
#pragma unroll
        for (int h = 0; h < H1; ++h) {
            const float* p = Ps + h * 9;
            Ls[n*8+h] = xv.x*p[0] + xv.y*p[1] + xv.z*p[2] + xv.w*p[3];
            Lr[n*8+h] = xv.x*p[4] + xv.y*p[5] + xv.z*p[6] + xv.w*p[7] + p[8];
        }
    }
}

// ---------------- CSR ----------------

__global__ __launch_bounds__(1024) void scan_rowptr(const int* __restrict__ deg,
                                                    int* __restrict__ rowptr,
                                                    int* __restrict__ cur) {
    __shared__ int wtot[16], wbase[16];
    int t = threadIdx.x, lane = t & 63, w = t >> 6;
    int base = t * 10;
    int vals[10]; int sum = 0;
#pragma unroll
    for (int i = 0; i < 10; ++i) {
        int idx = base + i;
        vals[i] = (idx < N_NODES) ? deg[idx] : 0;
        sum += vals[i];
    }
    int sc = sum;
#pragma unroll
    for (int off = 1; off < 64; off <<= 1) {
        int v = __shfl_up(sc, off, 64);
        if (lane >= off) sc += v;
    }
    if (lane == 63) wtot[w] = sc;
    __syncthreads();
    if (t < 16) {
        int v = wtot[t];
        int s2 = v;
#pragma unroll
        for (int off = 1; off < 16; off <<= 1) {
            int u = __shfl_up(s2, off, 64);
            if (t >= off) s2 += u;
        }
        wbase[t] = s2 - v;
        if (t == 15) rowptr[N_NODES] = s2;
    }
    __syncthreads();
    int run = wbase[w] + (sc - sum);
#pragma unroll
    for (int i = 0; i < 10; ++i) {
        int idx = base + i;
        if (idx < N_NODES) { rowptr[idx] = run; cur[idx] = run; }
        run += vals[i];
    }
}

__global__ void fill_csr(const int* __restrict__ ei, int* __restrict__ cur,
                         int* __restrict__ epos, int* __restrict__ slist) {
    int e = blockIdx.x * blockDim.x + threadIdx.x;
    if (e >= E_TOT) return;
    int s, d;
    if (e < N_EDGES) { s = ei[e]; d = ei[N_EDGES + e]; } else { s = e - N_EDGES; d = s; }
    int pos = atomicAdd(&cur[d], 1);
    epos[e] = pos;
    slist[pos] = s;
}

// ---------------- layer-1 logits -> exp(e), CSR-ordered ----------------
// 2 edges x 2 heads per thread; gridDim.y = 4 head-pairs; split src/dst chains.

__global__ __launch_bounds__(256) void logits1_v2(
        const int* __restrict__ ei, const uint2* __restrict__ xh,
        const uint4* __restrict__ WH, const float2* __restrict__ BA,
        const float* __restrict__ Ls, const float* __restrict__ Lr,
        const int* __restrict__ epos, float* __restrict__ e1) {
    int tid = threadIdx.x;
    int hg = blockIdx.y;                 // head pair {2hg, 2hg+1}
    int eA = blockIdx.x * 512 + tid;
    int eB = eA + 256;
    bool vA = eA < E_TOT, vB = eB < E_TOT;
    int eAc = vA ? eA : E_TOT - 1, eBc = vB ? eB : E_TOT - 1;
    int sA, dA, sB, dB;
    if (eAc < N_EDGES) { sA = ei[eAc]; dA = ei[N_EDGES + eAc]; } else { sA = eAc - N_EDGES; dA = sA; }
    if (eBc < N_EDGES) { sB = ei[eBc]; dB = ei[N_EDGES + eBc]; } else { sB = eBc - N_EDGES; dB = sB; }
    uint2 xsa = xh[sA], xda = xh[dA], xsb = xh[sB], xdb = xh[dB];
    float2 lsA = ((const float2*)Ls)[sA*4 + hg], lrA = ((const float2*)Lr)[dA*4 + hg];
    float2 lsB = ((const float2*)Ls)[sB*4 + hg], lrB = ((const float2*)Lr)[dB*4 + hg];
    int pA = epos[eAc], pB = epos[eBc];

    h2 xsa01 = toh2(xsa.x), xsa23 = toh2(xsa.y), xda01 = toh2(xda.x), xda23 = toh2(xda.y);
    h2 xsb01 = toh2(xsb.x), xsb23 = toh2(xsb.y), xdb01 = toh2(xdb.x), xdb23 = toh2(xdb.y);

    int cb = hg * 2 * C1;
    float aa0A = 0.f, aa1A = 0.f, aa0B = 0.f, aa1B = 0.f;
#pragma unroll 4
    for (int u = 0; u < C1; ++u) {
        {   // head 2hg
            uint4 wp = WH[cb + u]; float2 ba = BA[cb + u];
            h2 w0 = toh2(wp.x), w1 = toh2(wp.y), w2 = toh2(wp.z), w3 = toh2(wp.w);
            float t1 = FDOT2(xsa01, w0, ba.x); t1 = FDOT2(xsa23, w1, t1);
            float t2 = FDOT2(xda01, w2, 0.f);  t2 = FDOT2(xda23, w3, t2);
            aa0A = fmaf(ba.y, fabsf(t1 + t2), aa0A);
            float t3 = FDOT2(xsb01, w0, ba.x); t3 = FDOT2(xsb23, w1, t3);
            float t4 = FDOT2(xdb01, w2, 0.f);  t4 = FDOT2(xdb23, w3, t4);
            aa0B = fmaf(ba.y, fabsf(t3 + t4), aa0B);
        }
        {   // head 2hg+1
            uint4 wp = WH[cb + C1 + u]; float2 ba = BA[cb + C1 + u];
            h2 w0 = toh2(wp.x), w1 = toh2(wp.y), w2 = toh2(wp.z), w3 = toh2(wp.w);
            float t1 = FDOT2(xsa01, w0, ba.x); t1 = FDOT2(xsa23, w1, t1);
            float t2 = FDOT2(xda01, w2, 0.f);  t2 = FDOT2(xda23, w3, t2);
            aa1A = fmaf(ba.y, fabsf(t1 + t2), aa1A);
            float t3 = FDOT2(xsb01, w0, ba.x); t3 = FDOT2(xsb23, w1, t3);
            float t4 = FDOT2(xdb01, w2, 0.f);  t4 = FDOT2(xdb23, w3, t4);
            aa1B = fmaf(ba.y, fabsf(t3 + t4), aa1B);
        }
    }
    if (vA) {
        float2 o = make_float2(__expf(lsA.x + lrA.x + aa0A), __expf(lsA.y + lrA.y + aa1A));
        *(float2*)(e1 + (size_t)pA * 8 + hg * 2) = o;
    }
    if (vB) {
        float2 o = make_float2(__expf(lsB.x + lrB.x + aa0B), __expf(lsB.y + lrB.y + aa1B));
        *(float2*)(e1 + (size_t)pB * 8 + hg * 2) = o;
    }
}

// ---------------- layer-1 agg + f16 expand + relu + layer-2 transform ----------------
// 16 lanes per node, 16 nodes per block

#define AGG(hi, wv) { float W_ = (wv); ssum[hi] += W_; ag[hi].x += W_*xv.x; ag[hi].y += W_*xv.y; ag[hi].z += W_*xv.z; ag[hi].w += W_*xv.w; }

__global__ __launch_bounds__(256) void fused_agg1(
        const int* __restrict__ rowptr, const int* __restrict__ slist,
        const float* __restrict__ e1, const float* __restrict__ x,
        const uint2* __restrict__ WAh, const unsigned* __restrict__ PBh,
        const uint4* __restrict__ W2P,
        const float* __restrict__ b2l, const float* __restrict__ b2r,
        float* __restrict__ xl2, float* __restrict__ xr2) {
    int tid = threadIdx.x;
    int node = blockIdx.x * 16 + (tid >> 4);
    int l = tid & 15;
    int beg = rowptr[node], end = rowptr[node + 1];

    float ssum[H1]; float4 ag[H1];
#pragma unroll
    for (int h = 0; h < H1; ++h) { ssum[h] = 0.f; ag[h] = make_float4(0.f,0.f,0.f,0.f); }

    for (int i = beg + l; i < end; i += 16) {
        const float4* p = (const float4*)(e1 + (size_t)i * 8);
        float4 wa = p[0], wb = p[1];
        float4 xv = ((const float4*)x)[slist[i]];
        AGG(0, wa.x) AGG(1, wa.y) AGG(2, wa.z) AGG(3, wa.w)
        AGG(4, wb.x) AGG(5, wb.y) AGG(6, wb.z) AGG(7, wb.w)
    }
#pragma unroll
    for (int off = 8; off; off >>= 1) {
#pragma unroll
        for (int h = 0; h < H1; ++h) {
            ssum[h] += __shfl_xor(ssum[h], off, 64);
            ag[h].x += __shfl_xor(ag[h].x, off, 64);
            ag[h].y += __shfl_xor(ag[h].y, off, 64);
            ag[h].z += __shfl_xor(ag[h].z, off, 64);
            ag[h].w += __shfl_xor(ag[h].w, off, 64);
        }
    }
    // normalize, pack to f16
    unsigned agA[H1], agB[H1], sg[H1];
#pragma unroll
    for (int h = 0; h < H1; ++h) {
        float inv = 1.f / (ssum[h] + 1e-16f);
        agA[h] = packh2(ag[h].x * inv, ag[h].y * inv);
        agB[h] = packh2(ag[h].z * inv, ag[h].w * inv);
        sg[h]  = packh2(ssum[h] * inv, 1.f);
    }

    float al0=0, al1=0, al2=0, al3=0, ar0=0, ar1=0, ar2=0, ar3=0;
#pragma unroll
    for (int h = 0; h < H1; ++h) {
        h2 ga = toh2(agA[h]), gb = toh2(agB[h]), gs = toh2(sg[h]);
#pragma unroll
        for (int j = 0; j < 4; ++j) {
            int u = l + 16*j;
            if (u < 60) {
                int c0 = h*C1 + u;
                uint2 wa0 = WAh[c0];      unsigned pb0 = PBh[c0];
                uint2 wa1 = WAh[c0 + 60]; unsigned pb1 = PBh[c0 + 60];
                float f0 = FDOT2(gs, toh2(pb0), 0.f);
                f0 = FDOT2(ga, toh2(wa0.x), f0);
                f0 = FDOT2(gb, toh2(wa0.y), f0);
                f0 = fmaxf(f0, 0.f);
                float f1 = FDOT2(gs, toh2(pb1), 0.f);
                f1 = FDOT2(ga, toh2(wa1.x), f1);
                f1 = FDOT2(gb, toh2(wa1.y), f1);
                f1 = fmaxf(f1, 0.f);
                h2 hp = toh2(packh2(f0, f1));
                int pi = (h*60 + u) * 2;
                uint4 wA = W2P[pi], wB = W2P[pi + 1];
                al0 = FDOT2(hp, toh2(wA.x), al0); al1 = FDOT2(hp, toh2(wA.y), al1);
                al2 = FDOT2(hp, toh2(wA.z), al2); al3 = FDOT2(hp, toh2(wA.w), al3);
                ar0 = FDOT2(hp, toh2(wB.x), ar0); ar1 = FDOT2(hp, toh2(wB.y), ar1);
                ar2 = FDOT2(hp, toh2(wB.z), ar2); ar3 = FDOT2(hp, toh2(wB.w), ar3);
            }
        }
    }
#pragma unroll
    for (int off = 8; off; off >>= 1) {
        al0 += __shfl_xor(al0, off, 64); al1 += __shfl_xor(al1, off, 64);
        al2 += __shfl_xor(al2, off, 64); al3 += __shfl_xor(al3, off, 64);
        ar0 += __shfl_xor(ar0, off, 64); ar1 += __shfl_xor(ar1, off, 64);
        ar2 += __shfl_xor(ar2, off, 64); ar3 += __shfl_xor(ar3, off, 64);
    }
    if (l == 0) {
        ((float4*)xl2)[node] = make_float4(al0 + b2l[0], al1 + b2l[1], al2 + b2l[2], al3 + b2l[3]);
        ((float4*)xr2)[node] = make_float4(ar0 + b2r[0], ar1 + b2r[1], ar2 + b2r[2], ar3 + b2r[3]);
    }
}

// ---------------- layer-2 fused attention ----------------

__global__ __launch_bounds__(256) void attn2(
        const int* __restrict__ rowptr, const int* __restrict__ slist,
        const float* __restrict__ xl2, const float* __restrict__ xr2,
        const float* __restrict__ att2, const float* __restrict__ bias2,
        float* __restrict__ out) {
    int tid = threadIdx.x;
    int node = blockIdx.x * 16 + (tid >> 4);
    int l = tid & 15;
    int beg = rowptr[node], end = rowptr[node + 1];
    float4 xr = ((const float4*)xr2)[node];
    float a0 = att2[0], a1 = att2[1], a2 = att2[2], a3 = att2[3];

    float ssum = 0.f;
    float4 acc = make_float4(0.f, 0.f, 0.f, 0.f);
    for (int i = beg + l; i < end; i += 16) {
        float4 v = ((const float4*)xl2)[slist[i]];
        float lg = a0*lrelu(v.x + xr.x) + a1*lrelu(v.y + xr.y)
                 + a2*lrelu(v.z + xr.z) + a3*lrelu(v.w + xr.w);
        float w = __expf(lg);
        ssum += w;
        acc.x += w*v.x; acc.y += w*v.y; acc.z += w*v.z; acc.w += w*v.w;
    }
#pragma unroll
    for (int off = 8; off; off >>= 1) {
        ssum  += __shfl_xor(ssum,  off, 64);
        acc.x += __shfl_xor(acc.x, off, 64);
        acc.y += __shfl_xor(acc.y, off, 64);
        acc.z += __shfl_xor(acc.z, off, 64);
        acc.w += __shfl_xor(acc.w, off, 64);
    }
    if (l == 0) {
        float inv = 1.f / (ssum + 1e-16f);
        ((float4*)out)[node] = make_float4(acc.x*inv + bias2[0], acc.y*inv + bias2[1],
                                           acc.z*inv + bias2[2], acc.w*inv + bias2[3]);
    }
}

extern "C" void kernel_launch(void* const* d_in, const int* in_sizes, int n_in,
                              void* d_out, int out_size, void* d_ws, size_t ws_size,
                              hipStream_t stream) {
    const float* x     = (const float*)d_in[0];
    const int*   ei    = (const int*)  d_in[1];
    const float* W1l   = (const float*)d_in[2];
    const float* W1r   = (const float*)d_in[3];
    const float* b1l   = (const float*)d_in[4];
    const float* b1r   = (const float*)d_in[5];
    const float* att1  = (const float*)d_in[6];
    const float* bias1 = (const float*)d_in[7];
    const float* W2l   = (const float*)d_in[8];
    const float* W2r   = (const float*)d_in[9];
    const float* b2l   = (const float*)d_in[10];
    const float* b2r   = (const float*)d_in[11];
    const float* att2  = (const float*)d_in[12];
    const float* bias2 = (const float*)d_in[13];
    float* out = (float*)d_out;

    // workspace carve-up (segments 16B-aligned)
    float* e1   = (float*)d_ws;                   // E_TOT*8 = 1,360,000 f
    float* Ls   = e1 + (size_t)E_TOT * 8;         // 80,000
    float* Lr   = Ls + 80000;                     // 80,000
    float* xl2  = Lr + 80000;                     // 40,000
    float* xr2  = xl2 + 40000;                    // 40,000
    unsigned* WHu = (unsigned*)(xr2 + 40000);     // 3,840 (uint4[960])
    float* BAf  = (float*)(WHu + 3840);           // 1,920 (float2[960])
    unsigned* WAhu = (unsigned*)(BAf + 1920);     // 1,920 (uint2[960])
    unsigned* W2Pu = WAhu + 1920;                 // 7,680 (uint4[1920])
    unsigned* PBhu = W2Pu + 7680;                 // 960
    unsigned* xhu  = PBhu + 960;                  // 20,000 (uint2[10000])
    int* deg    = (int*)(xhu + 20000);            // 10,000
    int* rowptr = deg + 10000;                    // 10,004 (10,001 used)
    int* cur    = rowptr + 10004;                 // 10,000
    int* epos   = cur + 10000;                    // 170,000
    int* slist  = epos + 170000;                  // 170,000

    const int B = 256;

    hipMemsetAsync(deg, 0, 10000 * 4, stream);

    prep<<<44 + (E_TOT + B - 1) / B, B, 0, stream>>>(
        x, ei, W1l, W1r, b1l, b1r, att1, bias1, W2l, W2r,
        (uint4*)WHu, (float2*)BAf, (uint2*)WAhu, PBhu, (uint4*)W2Pu,
        (uint2*)xhu, Ls, Lr, deg);

    scan_rowptr<<<1, 1024, 0, stream>>>(deg, rowptr, cur);
    fill_csr<<<(E_TOT + B - 1) / B, B, 0, stream>>>(ei, cur, epos, slist);

    logits1_v2<<<dim3((E_TOT + 511) / 512, 4), B, 0, stream>>>(
        ei, (const uint2*)xhu, (const uint4*)WHu, (const float2*)BAf,
        Ls, Lr, epos, e1);
    fused_agg1<<<N_NODES / 16, B, 0, stream>>>(
        rowptr, slist, e1, x, (const uint2*)WAhu, PBhu, (const uint4*)W2Pu,
        b2l, b2r, xl2, xr2);
    attn2<<<N_NODES / 16, B, 0, stream>>>(rowptr, slist, xl2, xr2, att2, bias2, out);
}

// Round 9
// 126.514 us; speedup vs baseline: 2.3292x; 1.0594x over previous
//
#include <hip/hip_runtime.h>

#define N_NODES 10000
#define N_EDGES 160000
#define E_TOT   170000   // + self loops
#define N_TILES (E_TOT / 16)   // 10625 exactly
#define H1      8
#define C1      120
#define F1      960      // H1*C1

typedef _Float16 h2 __attribute__((ext_vector_type(2)));
typedef _Float16 f16x8 __attribute__((ext_vector_type(8)));
typedef float f32x4 __attribute__((ext_vector_type(4)));
union H2U { unsigned u; h2 h; };

#if defined(__has_builtin)
#if __has_builtin(__builtin_amdgcn_fdot2)
#define FDOT2(a,b,c) __builtin_amdgcn_fdot2((a),(b),(c),false)
#endif
#endif
#ifndef FDOT2
#define FDOT2(a,b,c) ((float)(a)[0]*(float)(b)[0] + (float)(a)[1]*(float)(b)[1] + (c))
#endif

__device__ __forceinline__ float lrelu(float v) { return fmaxf(v, 0.2f * v); }
__device__ __forceinline__ unsigned packh2(float a, float b) {
    H2U u; u.h = (h2){(_Float16)a, (_Float16)b}; return u.u;
}
__device__ __forceinline__ h2 toh2(unsigned v) { H2U u; u.u = v; return u.h; }

// ---------------- fused prep (+ deg_count) ----------------
// blocks 0..3 (t<240): c = b*240+t channel repack:
//   ATT[c] = 0.4*att1;  WAh[c] = f16x2 Wl column;  PBh[c] = pk(b1l, bias1)
//   Bp[ct*64 + g*16 + cl] MFMA B-frag table (ct=c/16, cl=c&15):
//     g0: {wl01,wl23,wr01,wr23}  g1: {pk(b,0),0,0,0}  g2,g3: 0
//   t<120: W2P pair tables for fused_agg1
// blocks 4..43: P (x0.6) in-block; 250 nodes each: xh pack, Ls, Lr
// blocks 44.. : deg_count (deg pre-zeroed by memset)
__global__ __launch_bounds__(256) void prep(
        const float* __restrict__ x, const int* __restrict__ ei,
        const float* __restrict__ W1l, const float* __restrict__ W1r,
        const float* __restrict__ b1l, const float* __restrict__ b1r,
        const float* __restrict__ att1, const float* __restrict__ bias1,
        const float* __restrict__ W2l, const float* __restrict__ W2r,
        uint4* __restrict__ Bp, float* __restrict__ ATT,
        uint2* __restrict__ WAh, unsigned* __restrict__ PBh,
        uint4* __restrict__ W2P,
        uint2* __restrict__ xh, float* __restrict__ Ls, float* __restrict__ Lr,
        int* __restrict__ deg) {
    int b = blockIdx.x, t = threadIdx.x;
    if (b >= 44) {
        int e = (b - 44) * 256 + t;
        if (e < E_TOT) {
            int d = (e < N_EDGES) ? ei[N_EDGES + e] : (e - N_EDGES);
            atomicAdd(&deg[d], 1);
        }
        return;
    }
    if (b < 4) {
        if (t < 240) {
            int c = b * 240 + t;
            float wl0 = W1l[c], wl1 = W1l[F1+c], wl2 = W1l[2*F1+c], wl3 = W1l[3*F1+c];
            float wr0 = W1r[c], wr1 = W1r[F1+c], wr2 = W1r[2*F1+c], wr3 = W1r[3*F1+c];
            float bc = b1l[c] + b1r[c];
            ATT[c] = 0.4f * att1[c];
            WAh[c] = make_uint2(packh2(wl0, wl1), packh2(wl2, wl3));
            PBh[c] = packh2(b1l[c], bias1[c]);
            int ct = c >> 4, cl = c & 15;
            Bp[ct*64 + cl]      = make_uint4(packh2(wl0, wl1), packh2(wl2, wl3),
                                             packh2(wr0, wr1), packh2(wr2, wr3));
            Bp[ct*64 + 16 + cl] = make_uint4(packh2(bc, 0.f), 0u, 0u, 0u);
            Bp[ct*64 + 32 + cl] = make_uint4(0u, 0u, 0u, 0u);
            Bp[ct*64 + 48 + cl] = make_uint4(0u, 0u, 0u, 0u);
        }
        if (t < 120) {
            int i = b * 120 + t;          // pair index: h = i/60, u = i%60
            int h = i / 60, u = i - h * 60;
            int c0 = h * C1 + u, c1 = c0 + 60;
            const float4 wl0 = ((const float4*)W2l)[c0], wl1 = ((const float4*)W2l)[c1];
            const float4 wr0 = ((const float4*)W2r)[c0], wr1 = ((const float4*)W2r)[c1];
            W2P[i*2]   = make_uint4(packh2(wl0.x, wl1.x), packh2(wl0.y, wl1.y),
                                    packh2(wl0.z, wl1.z), packh2(wl0.w, wl1.w));
            W2P[i*2+1] = make_uint4(packh2(wr0.x, wr1.x), packh2(wr0.y, wr1.y),
                                    packh2(wr0.z, wr1.z), packh2(wr0.w, wr1.w));
        }
        return;
    }
    __shared__ float Ps[72];
    if (t < 72) {
        int h = t / 9, j = t % 9;
        float acc = 0.f;
        for (int u = 0; u < C1; ++u) {
            int c = h * C1 + u;
            float a = att1[c];
            float w;
            if (j < 4)      w = W1l[j * F1 + c];
            else if (j < 8) w = W1r[(j - 4) * F1 + c];
            else            w = b1l[c] + b1r[c];
            acc = fmaf(a, w, acc);
        }
        Ps[t] = 0.6f * acc;
    }
    __syncthreads();
    int n = (b - 4) * 250 + t;
    if (t < 250) {
        float4 xv = ((const float4*)x)[n];
        xh[n] = make_uint2(packh2(xv.x, xv.y), packh2(xv.z, xv.w));
#pragma unroll
        for (int h = 0; h < H1; ++h) {
            const float* p = Ps + h * 9;
            Ls[n*8+h] = xv.x*p[0] + xv.y*p[1] + xv.z*p[2] + xv.w*p[3];
            Lr[n*8+h] = xv.x*p[4] + xv.y*p[5] + xv.z*p[6] + xv.w*p[7] + p[8];
        }
    }
}

// ---------------- CSR ----------------

__global__ __launch_bounds__(1024) void scan_rowptr(const int* __restrict__ deg,
                                                    int* __restrict__ rowptr,
                                                    int* __restrict__ cur) {
    __shared__ int wtot[16], wbase[16];
    int t = threadIdx.x, lane = t & 63, w = t >> 6;
    int base = t * 10;
    int vals[10]; int sum = 0;
#pragma unroll
    for (int i = 0; i < 10; ++i) {
        int idx = base + i;
        vals[i] = (idx < N_NODES) ? deg[idx] : 0;
        sum += vals[i];
    }
    int sc = sum;
#pragma unroll
    for (int off = 1; off < 64; off <<= 1) {
        int v = __shfl_up(sc, off, 64);
        if (lane >= off) sc += v;
    }
    if (lane == 63) wtot[w] = sc;
    __syncthreads();
    if (t < 16) {
        int v = wtot[t];
        int s2 = v;
#pragma unroll
        for (int off = 1; off < 16; off <<= 1) {
            int u = __shfl_up(s2, off, 64);
            if (t >= off) s2 += u;
        }
        wbase[t] = s2 - v;
        if (t == 15) rowptr[N_NODES] = s2;
    }
    __syncthreads();
    int run = wbase[w] + (sc - sum);
#pragma unroll
    for (int i = 0; i < 10; ++i) {
        int idx = base + i;
        if (idx < N_NODES) { rowptr[idx] = run; cur[idx] = run; }
        run += vals[i];
    }
}

__global__ void fill_csr(const int* __restrict__ ei, int* __restrict__ cur,
                         int* __restrict__ epos, int* __restrict__ slist) {
    int e = blockIdx.x * blockDim.x + threadIdx.x;
    if (e >= E_TOT) return;
    int s, d;
    if (e < N_EDGES) { s = ei[e]; d = ei[N_EDGES + e]; } else { s = e - N_EDGES; d = s; }
    int pos = atomicAdd(&cur[d], 1);
    epos[e] = pos;
    slist[pos] = s;
}

// ---------------- layer-1 logits via MFMA -> exp(e), CSR-ordered ----------------
// One wave per 16-edge tile. A = edges (k0-7 = [xs,xd], k8 = 1.0), B = Bp table
// (k0-7 = [wl,wr], k8 = b). 60 MFMA over channel tiles; epilogue att*|T| with
// per-head butterfly reduce at head boundaries (rem <= 16, wave-uniform).

__global__ __launch_bounds__(256) void logits_mfma(
        const int* __restrict__ ei, const uint2* __restrict__ xh,
        const uint4* __restrict__ Bp, const float* __restrict__ ATT,
        const float* __restrict__ Ls, const float* __restrict__ Lr,
        const int* __restrict__ epos, float* __restrict__ e1) {
    int tile = blockIdx.x * 4 + (threadIdx.x >> 6);
    if (tile >= N_TILES) return;
    int lane = threadIdx.x & 63;
    int cl = lane & 15, g = lane >> 4;
    int ebase = tile * 16;

    // A fragment: row = lane&15, k = g*8 + j
    union { uint4 u; f16x8 h; } au;
    au.u = make_uint4(0u, 0u, 0u, 0u);
    if (g == 0) {
        int er = ebase + cl;
        int s, d;
        if (er < N_EDGES) { s = ei[er]; d = ei[N_EDGES + er]; }
        else { s = er - N_EDGES; d = s; }
        uint2 a = xh[s], b = xh[d];
        au.u = make_uint4(a.x, a.y, b.x, b.y);
    } else if (g == 1) {
        au.u = make_uint4(0x00003C00u, 0u, 0u, 0u);   // k8 = 1.0 (bias row)
    }

    float aa0=0.f, aa1=0.f, aa2=0.f, aa3=0.f;   // current-head accum (4 rows)
    float k0=0.f, k1=0.f, k2=0.f, k3=0.f;       // kept heads (lane cl==h)
    int hcur = 0, nextEnd = C1;
    const uint4* bp = Bp + lane;
    const float* ap = ATT + cl;
#pragma unroll 5
    for (int ct = 0; ct < 60; ++ct) {
        union { uint4 u; f16x8 h; } bu; bu.u = bp[ct*64];
        float att = ap[ct*16];
        f32x4 dd = {0.f, 0.f, 0.f, 0.f};
        dd = __builtin_amdgcn_mfma_f32_16x16x32_f16(au.h, bu.h, dd, 0, 0, 0);
        float c0 = att*fabsf(dd[0]), c1 = att*fabsf(dd[1]),
              c2 = att*fabsf(dd[2]), c3 = att*fabsf(dd[3]);
        int rem = nextEnd - ct*16;
        if (rem <= 16) {   // head ends in this tile (wave-uniform)
            bool lo = cl < rem;
            aa0 += lo?c0:0.f; aa1 += lo?c1:0.f; aa2 += lo?c2:0.f; aa3 += lo?c3:0.f;
#pragma unroll
            for (int off = 1; off < 16; off <<= 1) {
                aa0 += __shfl_xor(aa0, off, 64);
                aa1 += __shfl_xor(aa1, off, 64);
                aa2 += __shfl_xor(aa2, off, 64);
                aa3 += __shfl_xor(aa3, off, 64);
            }
            bool p = (cl == hcur);
            k0 = p?aa0:k0; k1 = p?aa1:k1; k2 = p?aa2:k2; k3 = p?aa3:k3;
            aa0 = lo?0.f:c0; aa1 = lo?0.f:c1; aa2 = lo?0.f:c2; aa3 = lo?0.f:c3;
            hcur++; nextEnd += C1;
        } else {
            aa0 += c0; aa1 += c1; aa2 += c2; aa3 += c3;
        }
    }
    // write: lane (g, cl<8) holds head cl for edges ebase + g*4 + 0..3
    if (cl < H1) {
#pragma unroll
        for (int r = 0; r < 4; ++r) {
            int er = ebase + g*4 + r;
            int s, d;
            if (er < N_EDGES) { s = ei[er]; d = ei[N_EDGES + er]; }
            else { s = er - N_EDGES; d = s; }
            float lin = Ls[s*8 + cl] + Lr[d*8 + cl];
            float v = (r==0?k0 : r==1?k1 : r==2?k2 : k3);
            e1[(size_t)epos[er]*8 + cl] = __expf(lin + v);
        }
    }
}

// ---------------- layer-1 agg + f16 expand + relu + layer-2 transform ----------------
// 16 lanes per node, 16 nodes per block

#define AGG(hi, wv) { float W_ = (wv); ssum[hi] += W_; ag[hi].x += W_*xv.x; ag[hi].y += W_*xv.y; ag[hi].z += W_*xv.z; ag[hi].w += W_*xv.w; }

__global__ __launch_bounds__(256) void fused_agg1(
        const int* __restrict__ rowptr, const int* __restrict__ slist,
        const float* __restrict__ e1, const float* __restrict__ x,
        const uint2* __restrict__ WAh, const unsigned* __restrict__ PBh,
        const uint4* __restrict__ W2P,
        const float* __restrict__ b2l, const float* __restrict__ b2r,
        float* __restrict__ xl2, float* __restrict__ xr2) {
    int tid = threadIdx.x;
    int node = blockIdx.x * 16 + (tid >> 4);
    int l = tid & 15;
    int beg = rowptr[node], end = rowptr[node + 1];

    float ssum[H1]; float4 ag[H1];
#pragma unroll
    for (int h = 0; h < H1; ++h) { ssum[h] = 0.f; ag[h] = make_float4(0.f,0.f,0.f,0.f); }

    for (int i = beg + l; i < end; i += 16) {
        const float4* p = (const float4*)(e1 + (size_t)i * 8);
        float4 wa = p[0], wb = p[1];
        float4 xv = ((const float4*)x)[slist[i]];
        AGG(0, wa.x) AGG(1, wa.y) AGG(2, wa.z) AGG(3, wa.w)
        AGG(4, wb.x) AGG(5, wb.y) AGG(6, wb.z) AGG(7, wb.w)
    }
#pragma unroll
    for (int off = 8; off; off >>= 1) {
#pragma unroll
        for (int h = 0; h < H1; ++h) {
            ssum[h] += __shfl_xor(ssum[h], off, 64);
            ag[h].x += __shfl_xor(ag[h].x, off, 64);
            ag[h].y += __shfl_xor(ag[h].y, off, 64);
            ag[h].z += __shfl_xor(ag[h].z, off, 64);
            ag[h].w += __shfl_xor(ag[h].w, off, 64);
        }
    }
    unsigned agA[H1], agB[H1], sg[H1];
#pragma unroll
    for (int h = 0; h < H1; ++h) {
        float inv = 1.f / (ssum[h] + 1e-16f);
        agA[h] = packh2(ag[h].x * inv, ag[h].y * inv);
        agB[h] = packh2(ag[h].z * inv, ag[h].w * inv);
        sg[h]  = packh2(ssum[h] * inv, 1.f);
    }

    float al0=0, al1=0, al2=0, al3=0, ar0=0, ar1=0, ar2=0, ar3=0;
#pragma unroll
    for (int h = 0; h < H1; ++h) {
        h2 ga = toh2(agA[h]), gb = toh2(agB[h]), gs = toh2(sg[h]);
#pragma unroll
        for (int j = 0; j < 4; ++j) {
            int u = l + 16*j;
            if (u < 60) {
                int c0 = h*C1 + u;
                uint2 wa0 = WAh[c0];      unsigned pb0 = PBh[c0];
                uint2 wa1 = WAh[c0 + 60]; unsigned pb1 = PBh[c0 + 60];
                float f0 = FDOT2(gs, toh2(pb0), 0.f);
                f0 = FDOT2(ga, toh2(wa0.x), f0);
                f0 = FDOT2(gb, toh2(wa0.y), f0);
                f0 = fmaxf(f0, 0.f);
                float f1 = FDOT2(gs, toh2(pb1), 0.f);
                f1 = FDOT2(ga, toh2(wa1.x), f1);
                f1 = FDOT2(gb, toh2(wa1.y), f1);
                f1 = fmaxf(f1, 0.f);
                h2 hp = toh2(packh2(f0, f1));
                int pi = (h*60 + u) * 2;
                uint4 wA = W2P[pi], wB = W2P[pi + 1];
                al0 = FDOT2(hp, toh2(wA.x), al0); al1 = FDOT2(hp, toh2(wA.y), al1);
                al2 = FDOT2(hp, toh2(wA.z), al2); al3 = FDOT2(hp, toh2(wA.w), al3);
                ar0 = FDOT2(hp, toh2(wB.x), ar0); ar1 = FDOT2(hp, toh2(wB.y), ar1);
                ar2 = FDOT2(hp, toh2(wB.z), ar2); ar3 = FDOT2(hp, toh2(wB.w), ar3);
            }
        }
    }
#pragma unroll
    for (int off = 8; off; off >>= 1) {
        al0 += __shfl_xor(al0, off, 64); al1 += __shfl_xor(al1, off, 64);
        al2 += __shfl_xor(al2, off, 64); al3 += __shfl_xor(al3, off, 64);
        ar0 += __shfl_xor(ar0, off, 64); ar1 += __shfl_xor(ar1, off, 64);
        ar2 += __shfl_xor(ar2, off, 64); ar3 += __shfl_xor(ar3, off, 64);
    }
    if (l == 0) {
        ((float4*)xl2)[node] = make_float4(al0 + b2l[0], al1 + b2l[1], al2 + b2l[2], al3 + b2l[3]);
        ((float4*)xr2)[node] = make_float4(ar0 + b2r[0], ar1 + b2r[1], ar2 + b2r[2], ar3 + b2r[3]);
    }
}

// ---------------- layer-2 fused attention ----------------

__global__ __launch_bounds__(256) void attn2(
        const int* __restrict__ rowptr, const int* __restrict__ slist,
        const float* __restrict__ xl2, const float* __restrict__ xr2,
        const float* __restrict__ att2, const float* __restrict__ bias2,
        float* __restrict__ out) {
    int tid = threadIdx.x;
    int node = blockIdx.x * 16 + (tid >> 4);
    int l = tid & 15;
    int beg = rowptr[node], end = rowptr[node + 1];
    float4 xr = ((const float4*)xr2)[node];
    float a0 = att2[0], a1 = att2[1], a2 = att2[2], a3 = att2[3];

    float ssum = 0.f;
    float4 acc = make_float4(0.f, 0.f, 0.f, 0.f);
    for (int i = beg + l; i < end; i += 16) {
        float4 v = ((const float4*)xl2)[slist[i]];
        float lg = a0*lrelu(v.x + xr.x) + a1*lrelu(v.y + xr.y)
                 + a2*lrelu(v.z + xr.z) + a3*lrelu(v.w + xr.w);
        float w = __expf(lg);
        ssum += w;
        acc.x += w*v.x; acc.y += w*v.y; acc.z += w*v.z; acc.w += w*v.w;
    }
#pragma unroll
    for (int off = 8; off; off >>= 1) {
        ssum  += __shfl_xor(ssum,  off, 64);
        acc.x += __shfl_xor(acc.x, off, 64);
        acc.y += __shfl_xor(acc.y, off, 64);
        acc.z += __shfl_xor(acc.z, off, 64);
        acc.w += __shfl_xor(acc.w, off, 64);
    }
    if (l == 0) {
        float inv = 1.f / (ssum + 1e-16f);
        ((float4*)out)[node] = make_float4(acc.x*inv + bias2[0], acc.y*inv + bias2[1],
                                           acc.z*inv + bias2[2], acc.w*inv + bias2[3]);
    }
}

extern "C" void kernel_launch(void* const* d_in, const int* in_sizes, int n_in,
                              void* d_out, int out_size, void* d_ws, size_t ws_size,
                              hipStream_t stream) {
    const float* x     = (const float*)d_in[0];
    const int*   ei    = (const int*)  d_in[1];
    const float* W1l   = (const float*)d_in[2];
    const float* W1r   = (const float*)d_in[3];
    const float* b1l   = (const float*)d_in[4];
    const float* b1r   = (const float*)d_in[5];
    const float* att1  = (const float*)d_in[6];
    const float* bias1 = (const float*)d_in[7];
    const float* W2l   = (const float*)d_in[8];
    const float* W2r   = (const float*)d_in[9];
    const float* b2l   = (const float*)d_in[10];
    const float* b2r   = (const float*)d_in[11];
    const float* att2  = (const float*)d_in[12];
    const float* bias2 = (const float*)d_in[13];
    float* out = (float*)d_out;

    // workspace carve-up (segments 16B-aligned)
    float* e1   = (float*)d_ws;                   // E_TOT*8 = 1,360,000 f
    float* Ls   = e1 + (size_t)E_TOT * 8;         // 80,000
    float* Lr   = Ls + 80000;                     // 80,000
    float* xl2  = Lr + 80000;                     // 40,000
    float* xr2  = xl2 + 40000;                    // 40,000
    unsigned* Bpu  = (unsigned*)(xr2 + 40000);    // 15,360 (uint4[3840])
    float* ATT  = (float*)(Bpu + 15360);          // 960
    unsigned* WAhu = (unsigned*)(ATT + 960);      // 1,920 (uint2[960])
    unsigned* W2Pu = WAhu + 1920;                 // 7,680 (uint4[1920])
    unsigned* PBhu = W2Pu + 7680;                 // 960
    unsigned* xhu  = PBhu + 960;                  // 20,000 (uint2[10000])
    int* deg    = (int*)(xhu + 20000);            // 10,000
    int* rowptr = deg + 10000;                    // 10,004 (10,001 used)
    int* cur    = rowptr + 10004;                 // 10,000
    int* epos   = cur + 10000;                    // 170,000
    int* slist  = epos + 170000;                  // 170,000

    const int B = 256;

    hipMemsetAsync(deg, 0, 10000 * 4, stream);

    prep<<<44 + (E_TOT + B - 1) / B, B, 0, stream>>>(
        x, ei, W1l, W1r, b1l, b1r, att1, bias1, W2l, W2r,
        (uint4*)Bpu, ATT, (uint2*)WAhu, PBhu, (uint4*)W2Pu,
        (uint2*)xhu, Ls, Lr, deg);

    scan_rowptr<<<1, 1024, 0, stream>>>(deg, rowptr, cur);
    fill_csr<<<(E_TOT + B - 1) / B, B, 0, stream>>>(ei, cur, epos, slist);

    logits_mfma<<<(N_TILES + 3) / 4, B, 0, stream>>>(
        ei, (const uint2*)xhu, (const uint4*)Bpu, ATT, Ls, Lr, epos, e1);
    fused_agg1<<<N_NODES / 16, B, 0, stream>>>(
        rowptr, slist, e1, x, (const uint2*)WAhu, PBhu, (const uint4*)W2Pu,
        b2l, b2r, xl2, xr2);
    attn2<<<N_NODES / 16, B, 0, stream>>>(rowptr, slist, xl2, xr2, att2, bias2, out);
}